// Round 14
// baseline (164.869 us; speedup 1.0000x reference)
//
#include <hip/hip_runtime.h>
#include <hip/hip_bf16.h>

// R27 = R25 base (setprio reverted: R26 null -> lockstep loops have no role
// split for T5 to arbitrate).  k_attn restructured 256blk x 8w -> 512blk x 4w
// (2 blocks/CU): same 8 waves/CU, but barrier-DECOUPLED -- when one block
// drains at vmcnt+barrier the co-resident block's waves fill the SIMD
// (the mechanism R22 proved by losing it).  Staged K/V doubles 64->128MB;
// that VMEM work is what the other block hides.  Compute = R21 zero-move-P
// unchanged; staging = R18's proven 4-wave addressing (2+2 loads/wave/iter,
// vmcnt(4)).  k_prep/k_qkv/k_oln identical to R25.
// B=8, C=512, N=1024, NH=8, HD=64.

#define B_  8
#define C_  512
#define N_  1024
#define NH_ 8
#define HD_ 64

typedef __bf16 bf16x8 __attribute__((ext_vector_type(8)));
typedef __bf16 bf16x4 __attribute__((ext_vector_type(4)));
typedef float  f32x4  __attribute__((ext_vector_type(4)));

#define MFMA16(a, b, c) __builtin_amdgcn_mfma_f32_16x16x32_bf16((a), (b), (c), 0, 0, 0)

__device__ __forceinline__ void gload16(const void* g, void* l) {
    __builtin_amdgcn_global_load_lds(
        (const __attribute__((address_space(1))) unsigned int*)g,
        (__attribute__((address_space(3))) unsigned int*)l, 16, 0, 0);
}

// -------------------- K0: merged prep.  blk<1024: x -> xt; else weights -> wcat
__global__ __launch_bounds__(256) void k_prep(const float* __restrict__ x,
                                              const float* __restrict__ wq,
                                              const float* __restrict__ wk,
                                              const float* __restrict__ wv,
                                              const float* __restrict__ wo,
                                              __bf16* __restrict__ xt,
                                              __bf16* __restrict__ wcat) {
    __shared__ float tile[64][68];
    int blk = blockIdx.x;
    int tid = threadIdx.x;
    if (blk < 1024) {
        int b   = blk >> 7;
        int rem = blk & 127;
        int ct  = rem >> 4;
        int pt  = rem & 15;
        int c0 = ct * 64, p0 = pt * 64;
        for (int i = 0; i < 4; ++i) {
            int vi = i * 256 + tid;
            int c = vi >> 4, p4 = (vi & 15) * 4;
            f32x4 v = *(const f32x4*)(x + ((size_t)(b * C_ + c0 + c)) * N_ + p0 + p4);
            *(f32x4*)&tile[c][p4] = v;
        }
        __syncthreads();
        for (int i = 0; i < 4; ++i) {
            int vi = i * 256 + tid;
            int p = vi >> 4, c4 = (vi & 15) * 4;
            bf16x4 v;
            for (int j = 0; j < 4; ++j) v[j] = (__bf16)tile[c4 + j][p];
            *(bf16x4*)(xt + ((size_t)(b * N_ + p0 + p)) * C_ + c0 + c4) = v;
        }
    } else {
        int idx = (blk - 1024) * 256 + tid;
        int mat = idx >> 16;
        int off = (idx & 65535) * 4;
        const float* w = (mat == 0) ? wq : (mat == 1) ? wk : (mat == 2) ? wv : wo;
        f32x4 v = *(const f32x4*)(w + off);
        bf16x4 o;
        for (int j = 0; j < 4; ++j) o[j] = (__bf16)v[j];
        *(bf16x4*)(wcat + (size_t)mat * 262144 + off) = o;
    }
}

// ------------------------------------------------- K1: QKV projection (MFMA)
// 128x128 tile, BK=32, triple-buffered gload_lds staging, counted vmcnt.
// Q output pre-scaled by SCALE*log2(e) for k_attn's exp2.
__global__ __launch_bounds__(256) void k_qkv(const __bf16* __restrict__ xt,
                                             const __bf16* __restrict__ wcat,
                                             __bf16* __restrict__ qa,
                                             __bf16* __restrict__ ka,
                                             __bf16* __restrict__ vt) {
    __shared__ __bf16 As[3][4096];               // 3 x 8KB (128 rows x 64B)
    __shared__ __bf16 Bs[3][4096];
    int blk  = blockIdx.x;
    int mat  = blk >> 8;
    int rem  = blk & 255;
    int b    = rem >> 5;
    int tile = rem & 31;
    int tid = threadIdx.x, lane = tid & 63, wid = tid >> 6;
    int quad = lane >> 4, l16 = lane & 15;

    const __bf16* w = wcat + (size_t)mat * 262144;
    const __bf16 *A, *Bm;
    int am0, bn0;
    if (mat < 2) {
        int mt = tile >> 2, nt = tile & 3;
        A   = xt + (size_t)b * N_ * C_;  am0 = mt * 128;
        Bm  = w;                         bn0 = nt * 128;
    } else {
        int mt = tile & 3, nt = tile >> 2;
        A   = w;                         am0 = mt * 128;
        Bm  = xt + (size_t)b * N_ * C_;  bn0 = nt * 128;
    }
    int wr = (wid >> 1) * 64, wc = (wid & 1) * 64;   // wave tile offsets

    int lrow = wid * 16 + (lane >> 2);
    int scol = ((lane & 3) * 16) ^ ((lrow & 3) << 4);
    const char* aS0 = (const char*)A  + (size_t)(am0 + lrow) * 1024 + scol;
    const char* aS1 = aS0 + 65536;                   // +64 rows
    const char* bS0 = (const char*)Bm + (size_t)(bn0 + lrow) * 1024 + scol;
    const char* bS1 = bS0 + 65536;
    int wb = wid * 1024;

    // rotating buffer base pointers: R=read, N=next (landed), P=prefetch-dest
    char *aR = (char*)&As[0][0], *aN = (char*)&As[1][0], *aP = (char*)&As[2][0];
    char *bR = (char*)&Bs[0][0], *bN = (char*)&Bs[1][0], *bP = (char*)&Bs[2][0];

    // prologue: tiles 0,1 -> R,N (8 loads); wait tile0 (vmcnt<=4); barrier
    gload16(aS0,      aR + wb);  gload16(aS1,      aR + wb + 4096);
    gload16(bS0,      bR + wb);  gload16(bS1,      bR + wb + 4096);
    gload16(aS0 + 64, aN + wb);  gload16(aS1 + 64, aN + wb + 4096);
    gload16(bS0 + 64, bN + wb);  gload16(bS1 + 64, bN + wb + 4096);
    asm volatile("s_waitcnt vmcnt(4)" ::: "memory");
    __builtin_amdgcn_s_barrier();

    f32x4 acc[4][4] = {};
    const int fo = (quad * 16) ^ ((l16 & 3) << 4);   // frag byte col (swz'd)
    for (int t = 0; t < 16; ++t) {
        int kb = ((t + 2) & 15) * 64;                // tile t+2 byte offset
        gload16(aS0 + kb, aP + wb);  gload16(aS1 + kb, aP + wb + 4096);
        gload16(bS0 + kb, bP + wb);  gload16(bS1 + kb, bP + wb + 4096);

        bf16x8 af[4], bfr[4];
        for (int i = 0; i < 4; ++i)
            af[i]  = *(const bf16x8*)(aR + (wr + i * 16 + l16) * 64 + fo);
        for (int i = 0; i < 4; ++i)
            bfr[i] = *(const bf16x8*)(bR + (wc + i * 16 + l16) * 64 + fo);
        for (int mi = 0; mi < 4; ++mi)
            for (int ni = 0; ni < 4; ++ni)
                acc[mi][ni] = MFMA16(af[mi], bfr[ni], acc[mi][ni]);

        asm volatile("s_waitcnt vmcnt(4)" ::: "memory");   // tile t+1 landed
        __builtin_amdgcn_s_barrier();
        char* ta = aR; aR = aN; aN = aP; aP = ta;
        char* tb = bR; bR = bN; bN = bP; bP = tb;
    }

    if (mat < 2) {
        __bf16* dst = (mat == 0) ? qa : ka;
        float scl = (mat == 0) ? 0.18033688011112042f : 1.0f;  // SCALE*log2(e)
        for (int mi = 0; mi < 4; ++mi)
            for (int r = 0; r < 4; ++r) {
                int p = am0 + wr + mi * 16 + quad * 4 + r;
                int g = b * NH_ + (p >> 7);
                int nbase = (p & 127) * 8;
                for (int ni = 0; ni < 4; ++ni) {
                    int o = bn0 + wc + ni * 16 + l16;
                    dst[((size_t)g * N_ + nbase + (o >> 6)) * HD_ + (o & 63)] =
                        (__bf16)(acc[mi][ni][r] * scl);
                }
            }
    } else {
        for (int mi = 0; mi < 4; ++mi)
            for (int r = 0; r < 4; ++r) {
                int o = am0 + wr + mi * 16 + quad * 4 + r;
                int m = o & 63, i = o >> 6;
                for (int ni = 0; ni < 4; ++ni) {
                    int p = bn0 + wc + ni * 16 + l16;
                    int g = b * NH_ + (p >> 7);
                    vt[((size_t)g * HD_ + m) * N_ + (p & 127) * 8 + i] =
                        (__bf16)acc[mi][ni][r];
                }
            }
    }
}

// ----------------------------------------------------- K2: flash attention
// 512 blocks (XCD swizzle), 4 waves x 32 queries, 2 blocks/CU (barrier-
// decoupled).  Triple-buffered K/V staging (2+2 loads/wave/iter, vmcnt(4)).
// Zero-move P; Q pre-scaled -> exp2f(s) direct.
__global__ __launch_bounds__(256) void k_attn(const __bf16* __restrict__ qa,
                                              const __bf16* __restrict__ ka,
                                              const __bf16* __restrict__ vt,
                                              __bf16* __restrict__ ap) {
    __shared__ __bf16 Kb[3][4096];              // 3 x 8KB  (64 rows x 128B)
    __shared__ __bf16 Vb[3][4096];              // 3 x 8KB  (64 d-rows x 128B)
    int blk = blockIdx.x;
    int g  = ((blk & 7) << 3) | ((blk >> 3) & 7);
    int qb = blk >> 6;                          // 8 q-blocks of 128
    int tid = threadIdx.x, lane = tid & 63, wid = tid >> 6;   // wid 0..3
    int quad = lane >> 4, l16 = lane & 15;
    int q0 = qb * 128 + wid * 32;

    const __bf16* qp = qa + (size_t)g * N_ * HD_;
    const char* kbb = (const char*)(ka + (size_t)g * N_ * HD_);   // row j: 128B
    const char* vbb = (const char*)(vt + (size_t)g * HD_ * N_);   // row d: 2048B

    bf16x8 qA0 = *(const bf16x8*)(qp + (size_t)(q0 + l16) * HD_ + quad * 8);
    bf16x8 qA1 = *(const bf16x8*)(qp + (size_t)(q0 + l16) * HD_ + 32 + quad * 8);
    bf16x8 qB0 = *(const bf16x8*)(qp + (size_t)(q0 + 16 + l16) * HD_ + quad * 8);
    bf16x8 qB1 = *(const bf16x8*)(qp + (size_t)(q0 + 16 + l16) * HD_ + 32 + quad * 8);

    int lrow = lane >> 3;                              // row within 8-row chunk
    int scol = ((lane & 7) * 16) ^ (lrow << 4);        // inverse-swizzled src col
    const char* kSrc = kbb + (size_t)(wid * 16 + lrow) * 128  + scol;
    const char* vSrc = vbb + (size_t)(wid * 16 + lrow) * 2048 + scol;
    int wb = wid * 2048;                               // wave stages rows [16w,16w+16)

    char *kR = (char*)&Kb[0][0], *kN = (char*)&Kb[1][0], *kP = (char*)&Kb[2][0];
    char *vR = (char*)&Vb[0][0], *vN = (char*)&Vb[1][0], *vP = (char*)&Vb[2][0];

    // prologue: tiles 0,1 -> R,N (4+4 loads/wave); vmcnt(4) => tile0 landed
    gload16(kSrc,                 kR + wb);
    gload16(kSrc + 1024,          kR + wb + 1024);   // +8 rows
    gload16(vSrc,                 vR + wb);
    gload16(vSrc + 16384,         vR + wb + 1024);   // +8 d-rows
    gload16(kSrc + 8192,          kN + wb);          // tile1: +64 K-rows
    gload16(kSrc + 8192 + 1024,   kN + wb + 1024);
    gload16(vSrc + 128,           vN + wb);          // tile1: +64 kv-cols
    gload16(vSrc + 128 + 16384,   vN + wb + 1024);
    asm volatile("s_waitcnt vmcnt(4)" ::: "memory");
    __builtin_amdgcn_s_barrier();

    float liA = 0.f, liB = 0.f;
    f32x4 oA[4] = {}, oB[4] = {};
    const int fsw = (l16 & 7) << 4;                      // frag byte swizzle

    for (int t = 0; t < 16; ++t) {
        // 1) issue staging of tile t+2 into P (wraps on last iters; unused)
        int jn = ((t + 2) & 15) * 64;
        gload16(kSrc + (size_t)jn * 128,        kP + wb);
        gload16(kSrc + (size_t)jn * 128 + 1024, kP + wb + 1024);
        gload16(vSrc + jn * 2,                  vP + wb);
        gload16(vSrc + jn * 2 + 16384,          vP + wb + 1024);

        // 2) K frags from LDS + S-MFMA
        bf16x8 kc0[4], kc1[4];
#pragma unroll
        for (int tt = 0; tt < 4; ++tt) {
            int rb = (tt * 16 + l16) * 128;
            kc0[tt] = *(const bf16x8*)(kR + rb + ((quad * 16) ^ fsw));
            kc1[tt] = *(const bf16x8*)(kR + rb + ((64 + quad * 16) ^ fsw));
        }
        f32x4 sA[4] = {}, sB[4] = {};
#pragma unroll
        for (int tt = 0; tt < 4; ++tt) {
            sA[tt] = MFMA16(kc0[tt], qA0, sA[tt]);
            sA[tt] = MFMA16(kc1[tt], qA1, sA[tt]);
            sB[tt] = MFMA16(kc0[tt], qB0, sB[tt]);
            sB[tt] = MFMA16(kc1[tt], qB1, sB[tt]);
        }

        // 3) V frags: per (h,dd) two b64 reads merged via shufflevector
        bf16x8 av[2][4];
#pragma unroll
        for (int h = 0; h < 2; ++h)
#pragma unroll
            for (int dd = 0; dd < 4; ++dd) {
                int rb = (dd * 16 + l16) * 128;
                bf16x4 lo = *(const bf16x4*)(vR + rb + ((h * 64 + quad * 8) ^ fsw));
                bf16x4 hi = *(const bf16x4*)(vR + rb + ((h * 64 + 32 + quad * 8) ^ fsw));
                av[h][dd] = __builtin_shufflevector(lo, hi, 0, 1, 2, 3, 4, 5, 6, 7);
            }

        // 4) static softmax in-register (Q pre-scaled): P = exp2(s)
        bf16x8 paf[2], pbf[2];
#pragma unroll
        for (int tt = 0; tt < 4; ++tt)
#pragma unroll
            for (int r = 0; r < 4; ++r) {
                float pvA = exp2f(sA[tt][r]);
                float pvB = exp2f(sB[tt][r]);
                liA += pvA; liB += pvB;
                paf[tt >> 1][(tt & 1) * 4 + r] = (__bf16)pvA;
                pbf[tt >> 1][(tt & 1) * 4 + r] = (__bf16)pvB;
            }

        // 5) PV-MFMA (kv-bijection matches on both operands)
#pragma unroll
        for (int h = 0; h < 2; ++h)
#pragma unroll
            for (int dd = 0; dd < 4; ++dd) {
                oA[dd] = MFMA16(av[h][dd], paf[h], oA[dd]);
                oB[dd] = MFMA16(av[h][dd], pbf[h], oB[dd]);
            }

        // 6) tile t+1 landed (t+2's 4 loads stay in flight across barrier)
        asm volatile("s_waitcnt vmcnt(4)" ::: "memory");
        __builtin_amdgcn_s_barrier();
        char* tk = kR; kR = kN; kN = kP; kP = tk;
        char* tv = vR; vR = vN; vN = vP; vP = tv;
    }

    // one deferred li reduction across the 4 quads sharing each q
    liA += __shfl_xor(liA, 16, 64); liA += __shfl_xor(liA, 32, 64);
    liB += __shfl_xor(liB, 16, 64); liB += __shfl_xor(liB, 32, 64);

    int b = g >> 3, hi = g & 7;
    float invA = 1.0f / liA, invB = 1.0f / liB;
    int nA = q0 + l16, nB = q0 + 16 + l16;
    __bf16* dA = ap + ((size_t)(b * N_ + hi * 128 + (nA >> 3))) * C_ + (nA & 7) * 64;
    __bf16* dB = ap + ((size_t)(b * N_ + hi * 128 + (nB >> 3))) * C_ + (nB & 7) * 64;
#pragma unroll
    for (int dd = 0; dd < 4; ++dd) {
        bf16x4 oa, ob;
#pragma unroll
        for (int r = 0; r < 4; ++r) {
            oa[r] = (__bf16)(oA[dd][r] * invA);
            ob[r] = (__bf16)(oB[dd][r] * invB);
        }
        *(bf16x4*)(dA + dd * 16 + quad * 4) = oa;
        *(bf16x4*)(dB + dd * 16 + quad * 4) = ob;
    }
}

// ---------------- K3: FUSED out-projection + LN + residual -> out f32
// 256 blocks (8 b x 32 p-tiles of 32 rows) x 512 thr (8 waves, 1M x 8N).
// Per block: out[32p][512c] = ap[32x512] . wob^T, then LN over c + residual.
__global__ __launch_bounds__(512) void k_oln(const __bf16* __restrict__ apm,
                                             const __bf16* __restrict__ wob,
                                             const float* __restrict__ x,
                                             const float* __restrict__ lng,
                                             const float* __restrict__ lnb,
                                             const float* __restrict__ gm,
                                             float* __restrict__ out) {
    __shared__ __bf16 As[3][1024];               // 3 x 2KB  (32 rows x 64B)
    __shared__ __bf16 Bs[3][16384];              // 3 x 32KB (512 rows x 64B)
    __shared__ float  psum[8][32][2];            // per-wave LN partials, 2KB
    int blk = blockIdx.x;
    int b = blk >> 5, pt = blk & 31;
    int tid = threadIdx.x, lane = tid & 63, wid = tid >> 6;   // wid 0..7
    int quad = lane >> 4, l16 = lane & 15;
    float gv = gm[0];

    // staging addresses
    int arow = wid * 4 + (lane >> 2);            // valid when lane<16 (rows 4w..4w+3)
    int brow = wid * 16 + (lane >> 2);           // rows within 128-row chunk
    int scol = ((lane & 3) * 16) ^ (((lane >> 2) & 3) << 4);
    const char* aSrc = (const char*)apm + (size_t)(b * N_ + pt * 32 + arow) * 1024 + scol;
    const char* bSrc = (const char*)wob + (size_t)brow * 1024 + scol;

    char *aR = (char*)&As[0][0], *aN = (char*)&As[1][0], *aP = (char*)&As[2][0];
    char *bR = (char*)&Bs[0][0], *bN = (char*)&Bs[1][0], *bP = (char*)&Bs[2][0];
    int awb = wid * 256;                         // A: wave covers 4 rows = 256B
    int bwb = wid * 1024;                        // B: per-chunk wave offset

    // prologue: K-steps 0,1 (5 issues each); vmcnt(5) => step0 landed
    if (lane < 16) gload16(aSrc, aR + awb);
#pragma unroll
    for (int j = 0; j < 4; ++j)
        gload16(bSrc + (size_t)j * 131072, bR + j * 8192 + bwb);
    if (lane < 16) gload16(aSrc + 64, aN + awb);
#pragma unroll
    for (int j = 0; j < 4; ++j)
        gload16(bSrc + (size_t)j * 131072 + 64, bN + j * 8192 + bwb);
    asm volatile("s_waitcnt vmcnt(5)" ::: "memory");
    __builtin_amdgcn_s_barrier();

    f32x4 acc[2][4] = {};
    const int fo = (quad * 16) ^ ((l16 & 3) << 4);
    for (int t = 0; t < 16; ++t) {
        int kb = ((t + 2) & 15) * 64;
        if (lane < 16) gload16(aSrc + kb, aP + awb);
#pragma unroll
        for (int j = 0; j < 4; ++j)
            gload16(bSrc + (size_t)j * 131072 + kb, bP + j * 8192 + bwb);

        bf16x8 af[2], bfr[4];
#pragma unroll
        for (int i = 0; i < 2; ++i)
            af[i]  = *(const bf16x8*)(aR + (i * 16 + l16) * 64 + fo);
#pragma unroll
        for (int i = 0; i < 4; ++i)
            bfr[i] = *(const bf16x8*)(bR + (wid * 64 + i * 16 + l16) * 64 + fo);
#pragma unroll
        for (int mi = 0; mi < 2; ++mi)
#pragma unroll
            for (int ni = 0; ni < 4; ++ni)
                acc[mi][ni] = MFMA16(af[mi], bfr[ni], acc[mi][ni]);

        asm volatile("s_waitcnt vmcnt(5)" ::: "memory");   // step t+1 landed
        __builtin_amdgcn_s_barrier();
        char* ta = aR; aR = aN; aN = aP; aP = ta;
        char* tb = bR; bR = bN; bN = bP; bP = tb;
    }

    // ---- LN epilogue.  Thread owns p = mi*16+quad*4+r (8 vals),
    //      c = wid*64+ni*16+l16 (4 vals).
    float sm[2][4], sq[2][4];
#pragma unroll
    for (int mi = 0; mi < 2; ++mi)
#pragma unroll
        for (int r = 0; r < 4; ++r) {
            float s = 0.f, q = 0.f;
#pragma unroll
            for (int ni = 0; ni < 4; ++ni) {
                float v = acc[mi][ni][r];
                s += v; q += v * v;
            }
            s += __shfl_xor(s, 1, 64);  q += __shfl_xor(q, 1, 64);
            s += __shfl_xor(s, 2, 64);  q += __shfl_xor(q, 2, 64);
            s += __shfl_xor(s, 4, 64);  q += __shfl_xor(q, 4, 64);
            s += __shfl_xor(s, 8, 64);  q += __shfl_xor(q, 8, 64);
            sm[mi][r] = s; sq[mi][r] = q;
        }
    if (l16 == 0) {
#pragma unroll
        for (int mi = 0; mi < 2; ++mi)
#pragma unroll
            for (int r = 0; r < 4; ++r) {
                int p = mi * 16 + quad * 4 + r;
                psum[wid][p][0] = sm[mi][r];
                psum[wid][p][1] = sq[mi][r];
            }
    }
    __syncthreads();

    float mean[2][4], rstd[2][4];
#pragma unroll
    for (int mi = 0; mi < 2; ++mi)
#pragma unroll
        for (int r = 0; r < 4; ++r) {
            int p = mi * 16 + quad * 4 + r;
            float S = 0.f, Q = 0.f;
#pragma unroll
            for (int w = 0; w < 8; ++w) { S += psum[w][p][0]; Q += psum[w][p][1]; }
            float mn  = S * (1.f / 512.f);
            float var = Q * (1.f / 512.f) - mn * mn;
            mean[mi][r] = mn;
            rstd[mi][r] = rsqrtf(fmaxf(var, 0.f) + 1e-5f);
        }

    float lgv[4], lbv[4];
#pragma unroll
    for (int ni = 0; ni < 4; ++ni) {
        int c = wid * 64 + ni * 16 + l16;
        lgv[ni] = lng[c]; lbv[ni] = lnb[c];
    }
#pragma unroll
    for (int mi = 0; mi < 2; ++mi)
#pragma unroll
        for (int ni = 0; ni < 4; ++ni) {
            int c = wid * 64 + ni * 16 + l16;
            size_t base = ((size_t)(b * C_ + c)) * N_ + pt * 32 + mi * 16 + quad * 4;
            f32x4 xr = *(const f32x4*)(x + base);
            f32x4 o;
#pragma unroll
            for (int r = 0; r < 4; ++r)
                o[r] = gv * ((acc[mi][ni][r] - mean[mi][r]) * rstd[mi][r] * lgv[ni]
                             + lbv[ni]) + xr[r];
            *(f32x4*)(out + base) = o;
        }
}

// ======================= fallback (R8-proven scalar pipeline, f32)
__global__ void k_qkv8f(const float* __restrict__ x, const float* __restrict__ wq,
                        const float* __restrict__ wk, const float* __restrict__ wv,
                        float* __restrict__ qa, float* __restrict__ ka,
                        float* __restrict__ va, int g0) {
    int idx = blockIdx.x * 256 + threadIdx.x;
    int m = idx & 63, n = (idx >> 6) & 1023, Gl = (idx >> 16) & 1, mat = idx >> 17;
    int G = g0 + Gl, b = G >> 3, hb = G & 7;
    int p = hb * 128 + (n >> 3), o = (n & 7) * 64 + m;
    const float* w = (mat == 0) ? wq : (mat == 1) ? wk : wv;
    float acc = 0.f;
    for (int c = 0; c < C_; ++c)
        acc += w[(size_t)o * C_ + c] * x[((size_t)b * C_ + c) * N_ + p];
    float* dst = (mat == 0) ? qa : (mat == 1) ? ka : va;
    dst[((size_t)Gl * N_ + n) * HD_ + m] = acc;
}
__global__ void k_attn8f(const float* __restrict__ qa, const float* __restrict__ ka,
                         const float* __restrict__ va, float* __restrict__ ac, int g0) {
    int idx = blockIdx.x * 256 + threadIdx.x;
    int i = idx & 1023, Gl = (idx >> 10) & 1, G = g0 + Gl;
    const float* qrow = qa + ((size_t)Gl * N_ + i) * HD_;
    float q[HD_];
    for (int m = 0; m < HD_; ++m) q[m] = qrow[m];
    const float* kb = ka + (size_t)Gl * N_ * HD_;
    const float* vb = va + (size_t)Gl * N_ * HD_;
    float mx = -1e30f;
    for (int j = 0; j < N_; ++j) {
        float s = 0.f;
        for (int m = 0; m < HD_; ++m) s += q[m] * kb[j * HD_ + m];
        mx = fmaxf(mx, s);
    }
    mx *= 0.125f;
    float l = 0.f, ov[HD_];
    for (int m = 0; m < HD_; ++m) ov[m] = 0.f;
    for (int j = 0; j < N_; ++j) {
        float s = 0.f;
        for (int m = 0; m < HD_; ++m) s += q[m] * kb[j * HD_ + m];
        float pj = __expf(s * 0.125f - mx);
        l += pj;
        for (int m = 0; m < HD_; ++m) ov[m] += pj * vb[j * HD_ + m];
    }
    float inv = 1.0f / l;
    int b = G >> 3, hb = G & 7;
    int p = hb * 128 + (i >> 3), cb = (i & 7) * 64;
    for (int m = 0; m < HD_; ++m)
        ac[((size_t)b * C_ + cb + m) * N_ + p] = ov[m] * inv;
}
__global__ void k_oln8f(float* __restrict__ ac, const float* __restrict__ wo,
                        const float* __restrict__ x, const float* __restrict__ lng,
                        const float* __restrict__ lnb, const float* __restrict__ gm) {
    int tid = threadIdx.x, lane = tid & 63, wid = tid >> 6;
    int bp = blockIdx.x * 4 + wid;
    int b = bp >> 10, p = bp & 1023;
    float oc[8];
    for (int h = 0; h < 8; ++h) oc[h] = 0.f;
    for (int c = 0; c < C_; ++c) {
        float cv = ac[((size_t)b * C_ + c) * N_ + p];
        for (int h = 0; h < 8; ++h)
            oc[h] += wo[(size_t)(h * 64 + lane) * C_ + c] * cv;
    }
    float s = 0.f, ss = 0.f;
    for (int h = 0; h < 8; ++h) { s += oc[h]; ss += oc[h] * oc[h]; }
    for (int d = 1; d < 64; d <<= 1) { s += __shfl_xor(s, d, 64); ss += __shfl_xor(ss, d, 64); }
    float mean = s * (1.f / 512.f);
    float var  = ss * (1.f / 512.f) - mean * mean;
    float rstd = rsqrtf(fmaxf(var, 0.f) + 1e-5f);
    float g = gm[0];
    for (int h = 0; h < 8; ++h) {
        int o = h * 64 + lane;
        float xv = x[((size_t)b * C_ + o) * N_ + p];
        ac[((size_t)b * C_ + o) * N_ + p] =
            g * ((oc[h] - mean) * rstd * lng[o] + lnb[o]) + xv;
    }
}

// ---------------------------------------------------------------------------
extern "C" void kernel_launch(void* const* d_in, const int* in_sizes, int n_in,
                              void* d_out, int out_size, void* d_ws, size_t ws_size,
                              hipStream_t stream) {
    const float* x   = (const float*)d_in[0];
    const float* wq  = (const float*)d_in[1];
    const float* wk  = (const float*)d_in[2];
    const float* wv  = (const float*)d_in[3];
    const float* wo  = (const float*)d_in[4];
    const float* lng = (const float*)d_in[5];
    const float* lnb = (const float*)d_in[6];
    const float* gm  = (const float*)d_in[7];
    float* out = (float*)d_out;
    char* wsb = (char*)d_ws;

    if (ws_size >= ((size_t)18 << 20)) {
        __bf16* xt   = (__bf16*)wsb;
        __bf16* wcat = (__bf16*)(wsb + ((size_t)8 << 20));
        __bf16* Qa   = (__bf16*)(wsb + ((size_t)10 << 20));
        __bf16* Ka   = (__bf16*)d_out;
        __bf16* VaT  = (__bf16*)((char*)d_out + ((size_t)8 << 20));
        __bf16* ap   = xt;
        __bf16* wob  = wcat + 3 * 262144;

        k_prep <<<2048, 256, 0, stream>>>(x, wq, wk, wv, wo, xt, wcat);
        k_qkv  <<<768,  256, 0, stream>>>(xt, wcat, Qa, Ka, VaT);
        k_attn <<<512,  256, 0, stream>>>(Qa, Ka, VaT, ap);
        k_oln  <<<256,  512, 0, stream>>>(ap, wob, x, lng, lnb, gm, out);
    } else {
        float* qa = (float*)(wsb + 256);
        float* ka = qa + 2 * N_ * HD_;
        float* va = ka + 2 * N_ * HD_;
        for (int g0 = 0; g0 < 64; g0 += 2) {
            k_qkv8f <<<1536, 256, 0, stream>>>(x, wq, wk, wv, qa, ka, va, g0);
            k_attn8f<<<8,    256, 0, stream>>>(qa, ka, va, out, g0);
        }
        k_oln8f<<<2048, 256, 0, stream>>>(out, wo, x, lng, lnb, gm);
    }
}

// Round 15
// 162.025 us; speedup vs baseline: 1.0176x; 1.0176x over previous
//
#include <hip/hip_runtime.h>
#include <hip/hip_bf16.h>

// R28 == R25 verbatim (best measured: 163.0us).  Session close-out: R26
// (setprio) and R27 (2-blk/CU decoupling) were both null at +-1% -- the
// remaining gap to ideal (~15us compute vs ~104us kernel time) is the
// documented 2-phase structural ceiling, breakable only by 8-phase/256^2
// schedules this problem's grids cannot feed (R22: 1 blk/CU + idle CUs).
// Locking in the best-known config:
//  - k_prep: merged x-transpose + weight bf16 conversion
//  - k_qkv: 128^2 tiles, triple-buffer gload_lds, vmcnt(4), Q pre-scaled
//  - k_attn: 256blk x 8w, 3-buffer K/V staging vmcnt(2), zero-move P
//  - k_oln: fused oproj + LN + residual (vmcnt(5) staging, LN in epilogue)
// B=8, C=512, N=1024, NH=8, HD=64.

#define B_  8
#define C_  512
#define N_  1024
#define NH_ 8
#define HD_ 64

typedef __bf16 bf16x8 __attribute__((ext_vector_type(8)));
typedef __bf16 bf16x4 __attribute__((ext_vector_type(4)));
typedef float  f32x4  __attribute__((ext_vector_type(4)));

#define MFMA16(a, b, c) __builtin_amdgcn_mfma_f32_16x16x32_bf16((a), (b), (c), 0, 0, 0)

__device__ __forceinline__ void gload16(const void* g, void* l) {
    __builtin_amdgcn_global_load_lds(
        (const __attribute__((address_space(1))) unsigned int*)g,
        (__attribute__((address_space(3))) unsigned int*)l, 16, 0, 0);
}

// -------------------- K0: merged prep.  blk<1024: x -> xt; else weights -> wcat
__global__ __launch_bounds__(256) void k_prep(const float* __restrict__ x,
                                              const float* __restrict__ wq,
                                              const float* __restrict__ wk,
                                              const float* __restrict__ wv,
                                              const float* __restrict__ wo,
                                              __bf16* __restrict__ xt,
                                              __bf16* __restrict__ wcat) {
    __shared__ float tile[64][68];
    int blk = blockIdx.x;
    int tid = threadIdx.x;
    if (blk < 1024) {
        int b   = blk >> 7;
        int rem = blk & 127;
        int ct  = rem >> 4;
        int pt  = rem & 15;
        int c0 = ct * 64, p0 = pt * 64;
        for (int i = 0; i < 4; ++i) {
            int vi = i * 256 + tid;
            int c = vi >> 4, p4 = (vi & 15) * 4;
            f32x4 v = *(const f32x4*)(x + ((size_t)(b * C_ + c0 + c)) * N_ + p0 + p4);
            *(f32x4*)&tile[c][p4] = v;
        }
        __syncthreads();
        for (int i = 0; i < 4; ++i) {
            int vi = i * 256 + tid;
            int p = vi >> 4, c4 = (vi & 15) * 4;
            bf16x4 v;
            for (int j = 0; j < 4; ++j) v[j] = (__bf16)tile[c4 + j][p];
            *(bf16x4*)(xt + ((size_t)(b * N_ + p0 + p)) * C_ + c0 + c4) = v;
        }
    } else {
        int idx = (blk - 1024) * 256 + tid;
        int mat = idx >> 16;
        int off = (idx & 65535) * 4;
        const float* w = (mat == 0) ? wq : (mat == 1) ? wk : (mat == 2) ? wv : wo;
        f32x4 v = *(const f32x4*)(w + off);
        bf16x4 o;
        for (int j = 0; j < 4; ++j) o[j] = (__bf16)v[j];
        *(bf16x4*)(wcat + (size_t)mat * 262144 + off) = o;
    }
}

// ------------------------------------------------- K1: QKV projection (MFMA)
// 128x128 tile, BK=32, triple-buffered gload_lds staging, counted vmcnt.
// Q output pre-scaled by SCALE*log2(e) for k_attn's exp2.
__global__ __launch_bounds__(256) void k_qkv(const __bf16* __restrict__ xt,
                                             const __bf16* __restrict__ wcat,
                                             __bf16* __restrict__ qa,
                                             __bf16* __restrict__ ka,
                                             __bf16* __restrict__ vt) {
    __shared__ __bf16 As[3][4096];               // 3 x 8KB (128 rows x 64B)
    __shared__ __bf16 Bs[3][4096];
    int blk  = blockIdx.x;
    int mat  = blk >> 8;
    int rem  = blk & 255;
    int b    = rem >> 5;
    int tile = rem & 31;
    int tid = threadIdx.x, lane = tid & 63, wid = tid >> 6;
    int quad = lane >> 4, l16 = lane & 15;

    const __bf16* w = wcat + (size_t)mat * 262144;
    const __bf16 *A, *Bm;
    int am0, bn0;
    if (mat < 2) {
        int mt = tile >> 2, nt = tile & 3;
        A   = xt + (size_t)b * N_ * C_;  am0 = mt * 128;
        Bm  = w;                         bn0 = nt * 128;
    } else {
        int mt = tile & 3, nt = tile >> 2;
        A   = w;                         am0 = mt * 128;
        Bm  = xt + (size_t)b * N_ * C_;  bn0 = nt * 128;
    }
    int wr = (wid >> 1) * 64, wc = (wid & 1) * 64;   // wave tile offsets

    int lrow = wid * 16 + (lane >> 2);
    int scol = ((lane & 3) * 16) ^ ((lrow & 3) << 4);
    const char* aS0 = (const char*)A  + (size_t)(am0 + lrow) * 1024 + scol;
    const char* aS1 = aS0 + 65536;                   // +64 rows
    const char* bS0 = (const char*)Bm + (size_t)(bn0 + lrow) * 1024 + scol;
    const char* bS1 = bS0 + 65536;
    int wb = wid * 1024;

    // rotating buffer base pointers: R=read, N=next (landed), P=prefetch-dest
    char *aR = (char*)&As[0][0], *aN = (char*)&As[1][0], *aP = (char*)&As[2][0];
    char *bR = (char*)&Bs[0][0], *bN = (char*)&Bs[1][0], *bP = (char*)&Bs[2][0];

    // prologue: tiles 0,1 -> R,N (8 loads); wait tile0 (vmcnt<=4); barrier
    gload16(aS0,      aR + wb);  gload16(aS1,      aR + wb + 4096);
    gload16(bS0,      bR + wb);  gload16(bS1,      bR + wb + 4096);
    gload16(aS0 + 64, aN + wb);  gload16(aS1 + 64, aN + wb + 4096);
    gload16(bS0 + 64, bN + wb);  gload16(bS1 + 64, bN + wb + 4096);
    asm volatile("s_waitcnt vmcnt(4)" ::: "memory");
    __builtin_amdgcn_s_barrier();

    f32x4 acc[4][4] = {};
    const int fo = (quad * 16) ^ ((l16 & 3) << 4);   // frag byte col (swz'd)
    for (int t = 0; t < 16; ++t) {
        int kb = ((t + 2) & 15) * 64;                // tile t+2 byte offset
        gload16(aS0 + kb, aP + wb);  gload16(aS1 + kb, aP + wb + 4096);
        gload16(bS0 + kb, bP + wb);  gload16(bS1 + kb, bP + wb + 4096);

        bf16x8 af[4], bfr[4];
        for (int i = 0; i < 4; ++i)
            af[i]  = *(const bf16x8*)(aR + (wr + i * 16 + l16) * 64 + fo);
        for (int i = 0; i < 4; ++i)
            bfr[i] = *(const bf16x8*)(bR + (wc + i * 16 + l16) * 64 + fo);
        for (int mi = 0; mi < 4; ++mi)
            for (int ni = 0; ni < 4; ++ni)
                acc[mi][ni] = MFMA16(af[mi], bfr[ni], acc[mi][ni]);

        asm volatile("s_waitcnt vmcnt(4)" ::: "memory");   // tile t+1 landed
        __builtin_amdgcn_s_barrier();
        char* ta = aR; aR = aN; aN = aP; aP = ta;
        char* tb = bR; bR = bN; bN = bP; bP = tb;
    }

    if (mat < 2) {
        __bf16* dst = (mat == 0) ? qa : ka;
        float scl = (mat == 0) ? 0.18033688011112042f : 1.0f;  // SCALE*log2(e)
        for (int mi = 0; mi < 4; ++mi)
            for (int r = 0; r < 4; ++r) {
                int p = am0 + wr + mi * 16 + quad * 4 + r;
                int g = b * NH_ + (p >> 7);
                int nbase = (p & 127) * 8;
                for (int ni = 0; ni < 4; ++ni) {
                    int o = bn0 + wc + ni * 16 + l16;
                    dst[((size_t)g * N_ + nbase + (o >> 6)) * HD_ + (o & 63)] =
                        (__bf16)(acc[mi][ni][r] * scl);
                }
            }
    } else {
        for (int mi = 0; mi < 4; ++mi)
            for (int r = 0; r < 4; ++r) {
                int o = am0 + wr + mi * 16 + quad * 4 + r;
                int m = o & 63, i = o >> 6;
                for (int ni = 0; ni < 4; ++ni) {
                    int p = bn0 + wc + ni * 16 + l16;
                    int g = b * NH_ + (p >> 7);
                    vt[((size_t)g * HD_ + m) * N_ + (p & 127) * 8 + i] =
                        (__bf16)acc[mi][ni][r];
                }
            }
    }
}

// ----------------------------------------------------- K2: flash attention
// R21-exact structure: 256 blocks (XCD swizzle), 8 waves x 32 queries,
// 3-buffer rotation, vmcnt(2).  Zero-move P; Q pre-scaled -> exp2f(s) direct.
__global__ __launch_bounds__(512) void k_attn(const __bf16* __restrict__ qa,
                                              const __bf16* __restrict__ ka,
                                              const __bf16* __restrict__ vt,
                                              __bf16* __restrict__ ap) {
    __shared__ __bf16 Kb[3][4096];              // 3 x 8KB  (64 rows x 128B)
    __shared__ __bf16 Vb[3][4096];              // 3 x 8KB  (64 d-rows x 128B)
    int blk = blockIdx.x;
    int g  = ((blk & 7) << 3) | ((blk >> 3) & 7);
    int qb = blk >> 6;                          // 4 q-blocks of 256
    int tid = threadIdx.x, lane = tid & 63, wid = tid >> 6;   // wid 0..7
    int quad = lane >> 4, l16 = lane & 15;
    int q0 = qb * 256 + wid * 32;

    const __bf16* qp = qa + (size_t)g * N_ * HD_;
    const char* kbb = (const char*)(ka + (size_t)g * N_ * HD_);   // row j: 128B
    const char* vbb = (const char*)(vt + (size_t)g * HD_ * N_);   // row d: 2048B

    bf16x8 qA0 = *(const bf16x8*)(qp + (size_t)(q0 + l16) * HD_ + quad * 8);
    bf16x8 qA1 = *(const bf16x8*)(qp + (size_t)(q0 + l16) * HD_ + 32 + quad * 8);
    bf16x8 qB0 = *(const bf16x8*)(qp + (size_t)(q0 + 16 + l16) * HD_ + quad * 8);
    bf16x8 qB1 = *(const bf16x8*)(qp + (size_t)(q0 + 16 + l16) * HD_ + 32 + quad * 8);

    int lrow = lane >> 3;                              // row within 8-row chunk
    int scol = ((lane & 7) * 16) ^ (lrow << 4);        // inverse-swizzled src col
    const char* kSrc = kbb + (size_t)(wid * 8 + lrow) * 128  + scol;
    const char* vSrc = vbb + (size_t)(wid * 8 + lrow) * 2048 + scol;
    int wb = wid * 1024;                               // wave stages rows [8w,8w+8)

    char *kR = (char*)&Kb[0][0], *kN = (char*)&Kb[1][0], *kP = (char*)&Kb[2][0];
    char *vR = (char*)&Vb[0][0], *vN = (char*)&Vb[1][0], *vP = (char*)&Vb[2][0];

    // prologue: tiles 0,1 -> R,N (2+2 loads/wave); wait tile0; barrier
    gload16(kSrc,        kR + wb);
    gload16(vSrc,        vR + wb);
    gload16(kSrc + 8192, kN + wb);     // tile1: +64 K-rows
    gload16(vSrc + 128,  vN + wb);     // tile1: +64 kv-cols
    asm volatile("s_waitcnt vmcnt(2)" ::: "memory");
    __builtin_amdgcn_s_barrier();

    float liA = 0.f, liB = 0.f;
    f32x4 oA[4] = {}, oB[4] = {};
    const int fsw = (l16 & 7) << 4;                      // frag byte swizzle

    for (int t = 0; t < 16; ++t) {
        // 1) issue staging of tile t+2 into P (wraps on last iters; unused)
        int jn = ((t + 2) & 15) * 64;
        gload16(kSrc + (size_t)jn * 128, kP + wb);
        gload16(vSrc + jn * 2,           vP + wb);

        // 2) K frags from LDS + S-MFMA
        bf16x8 kc0[4], kc1[4];
#pragma unroll
        for (int tt = 0; tt < 4; ++tt) {
            int rb = (tt * 16 + l16) * 128;
            kc0[tt] = *(const bf16x8*)(kR + rb + ((quad * 16) ^ fsw));
            kc1[tt] = *(const bf16x8*)(kR + rb + ((64 + quad * 16) ^ fsw));
        }
        f32x4 sA[4] = {}, sB[4] = {};
#pragma unroll
        for (int tt = 0; tt < 4; ++tt) {
            sA[tt] = MFMA16(kc0[tt], qA0, sA[tt]);
            sA[tt] = MFMA16(kc1[tt], qA1, sA[tt]);
            sB[tt] = MFMA16(kc0[tt], qB0, sB[tt]);
            sB[tt] = MFMA16(kc1[tt], qB1, sB[tt]);
        }

        // 3) V frags: per (h,dd) two b64 reads merged via shufflevector
        bf16x8 av[2][4];
#pragma unroll
        for (int h = 0; h < 2; ++h)
#pragma unroll
            for (int dd = 0; dd < 4; ++dd) {
                int rb = (dd * 16 + l16) * 128;
                bf16x4 lo = *(const bf16x4*)(vR + rb + ((h * 64 + quad * 8) ^ fsw));
                bf16x4 hi = *(const bf16x4*)(vR + rb + ((h * 64 + 32 + quad * 8) ^ fsw));
                av[h][dd] = __builtin_shufflevector(lo, hi, 0, 1, 2, 3, 4, 5, 6, 7);
            }

        // 4) static softmax in-register (Q pre-scaled): P = exp2(s)
        bf16x8 paf[2], pbf[2];
#pragma unroll
        for (int tt = 0; tt < 4; ++tt)
#pragma unroll
            for (int r = 0; r < 4; ++r) {
                float pvA = exp2f(sA[tt][r]);
                float pvB = exp2f(sB[tt][r]);
                liA += pvA; liB += pvB;
                paf[tt >> 1][(tt & 1) * 4 + r] = (__bf16)pvA;
                pbf[tt >> 1][(tt & 1) * 4 + r] = (__bf16)pvB;
            }

        // 5) PV-MFMA (kv-bijection matches on both operands)
#pragma unroll
        for (int h = 0; h < 2; ++h)
#pragma unroll
            for (int dd = 0; dd < 4; ++dd) {
                oA[dd] = MFMA16(av[h][dd], paf[h], oA[dd]);
                oB[dd] = MFMA16(av[h][dd], pbf[h], oB[dd]);
            }

        // 6) tile t+1 landed (t+2's 2 loads stay in flight across barrier)
        asm volatile("s_waitcnt vmcnt(2)" ::: "memory");
        __builtin_amdgcn_s_barrier();
        char* tk = kR; kR = kN; kN = kP; kP = tk;
        char* tv = vR; vR = vN; vN = vP; vP = tv;
    }

    // one deferred li reduction across the 4 quads sharing each q
    liA += __shfl_xor(liA, 16, 64); liA += __shfl_xor(liA, 32, 64);
    liB += __shfl_xor(liB, 16, 64); liB += __shfl_xor(liB, 32, 64);

    int b = g >> 3, hi = g & 7;
    float invA = 1.0f / liA, invB = 1.0f / liB;
    int nA = q0 + l16, nB = q0 + 16 + l16;
    __bf16* dA = ap + ((size_t)(b * N_ + hi * 128 + (nA >> 3))) * C_ + (nA & 7) * 64;
    __bf16* dB = ap + ((size_t)(b * N_ + hi * 128 + (nB >> 3))) * C_ + (nB & 7) * 64;
#pragma unroll
    for (int dd = 0; dd < 4; ++dd) {
        bf16x4 oa, ob;
#pragma unroll
        for (int r = 0; r < 4; ++r) {
            oa[r] = (__bf16)(oA[dd][r] * invA);
            ob[r] = (__bf16)(oB[dd][r] * invB);
        }
        *(bf16x4*)(dA + dd * 16 + quad * 4) = oa;
        *(bf16x4*)(dB + dd * 16 + quad * 4) = ob;
    }
}

// ---------------- K3: FUSED out-projection + LN + residual -> out f32
// 256 blocks (8 b x 32 p-tiles of 32 rows) x 512 thr (8 waves, 1M x 8N).
// Per block: out[32p][512c] = ap[32x512] . wob^T, then LN over c + residual.
__global__ __launch_bounds__(512) void k_oln(const __bf16* __restrict__ apm,
                                             const __bf16* __restrict__ wob,
                                             const float* __restrict__ x,
                                             const float* __restrict__ lng,
                                             const float* __restrict__ lnb,
                                             const float* __restrict__ gm,
                                             float* __restrict__ out) {
    __shared__ __bf16 As[3][1024];               // 3 x 2KB  (32 rows x 64B)
    __shared__ __bf16 Bs[3][16384];              // 3 x 32KB (512 rows x 64B)
    __shared__ float  psum[8][32][2];            // per-wave LN partials, 2KB
    int blk = blockIdx.x;
    int b = blk >> 5, pt = blk & 31;
    int tid = threadIdx.x, lane = tid & 63, wid = tid >> 6;   // wid 0..7
    int quad = lane >> 4, l16 = lane & 15;
    float gv = gm[0];

    // staging addresses
    int arow = wid * 4 + (lane >> 2);            // valid when lane<16 (rows 4w..4w+3)
    int brow = wid * 16 + (lane >> 2);           // rows within 128-row chunk
    int scol = ((lane & 3) * 16) ^ (((lane >> 2) & 3) << 4);
    const char* aSrc = (const char*)apm + (size_t)(b * N_ + pt * 32 + arow) * 1024 + scol;
    const char* bSrc = (const char*)wob + (size_t)brow * 1024 + scol;

    char *aR = (char*)&As[0][0], *aN = (char*)&As[1][0], *aP = (char*)&As[2][0];
    char *bR = (char*)&Bs[0][0], *bN = (char*)&Bs[1][0], *bP = (char*)&Bs[2][0];
    int awb = wid * 256;                         // A: wave covers 4 rows = 256B
    int bwb = wid * 1024;                        // B: per-chunk wave offset

    // prologue: K-steps 0,1 (5 issues each); vmcnt(5) => step0 landed
    if (lane < 16) gload16(aSrc, aR + awb);
#pragma unroll
    for (int j = 0; j < 4; ++j)
        gload16(bSrc + (size_t)j * 131072, bR + j * 8192 + bwb);
    if (lane < 16) gload16(aSrc + 64, aN + awb);
#pragma unroll
    for (int j = 0; j < 4; ++j)
        gload16(bSrc + (size_t)j * 131072 + 64, bN + j * 8192 + bwb);
    asm volatile("s_waitcnt vmcnt(5)" ::: "memory");
    __builtin_amdgcn_s_barrier();

    f32x4 acc[2][4] = {};
    const int fo = (quad * 16) ^ ((l16 & 3) << 4);
    for (int t = 0; t < 16; ++t) {
        int kb = ((t + 2) & 15) * 64;
        if (lane < 16) gload16(aSrc + kb, aP + awb);
#pragma unroll
        for (int j = 0; j < 4; ++j)
            gload16(bSrc + (size_t)j * 131072 + kb, bP + j * 8192 + bwb);

        bf16x8 af[2], bfr[4];
#pragma unroll
        for (int i = 0; i < 2; ++i)
            af[i]  = *(const bf16x8*)(aR + (i * 16 + l16) * 64 + fo);
#pragma unroll
        for (int i = 0; i < 4; ++i)
            bfr[i] = *(const bf16x8*)(bR + (wid * 64 + i * 16 + l16) * 64 + fo);
#pragma unroll
        for (int mi = 0; mi < 2; ++mi)
#pragma unroll
            for (int ni = 0; ni < 4; ++ni)
                acc[mi][ni] = MFMA16(af[mi], bfr[ni], acc[mi][ni]);

        asm volatile("s_waitcnt vmcnt(5)" ::: "memory");   // step t+1 landed
        __builtin_amdgcn_s_barrier();
        char* ta = aR; aR = aN; aN = aP; aP = ta;
        char* tb = bR; bR = bN; bN = bP; bP = tb;
    }

    // ---- LN epilogue.  Thread owns p = mi*16+quad*4+r (8 vals),
    //      c = wid*64+ni*16+l16 (4 vals).
    float sm[2][4], sq[2][4];
#pragma unroll
    for (int mi = 0; mi < 2; ++mi)
#pragma unroll
        for (int r = 0; r < 4; ++r) {
            float s = 0.f, q = 0.f;
#pragma unroll
            for (int ni = 0; ni < 4; ++ni) {
                float v = acc[mi][ni][r];
                s += v; q += v * v;
            }
            s += __shfl_xor(s, 1, 64);  q += __shfl_xor(q, 1, 64);
            s += __shfl_xor(s, 2, 64);  q += __shfl_xor(q, 2, 64);
            s += __shfl_xor(s, 4, 64);  q += __shfl_xor(q, 4, 64);
            s += __shfl_xor(s, 8, 64);  q += __shfl_xor(q, 8, 64);
            sm[mi][r] = s; sq[mi][r] = q;
        }
    if (l16 == 0) {
#pragma unroll
        for (int mi = 0; mi < 2; ++mi)
#pragma unroll
            for (int r = 0; r < 4; ++r) {
                int p = mi * 16 + quad * 4 + r;
                psum[wid][p][0] = sm[mi][r];
                psum[wid][p][1] = sq[mi][r];
            }
    }
    __syncthreads();

    float mean[2][4], rstd[2][4];
#pragma unroll
    for (int mi = 0; mi < 2; ++mi)
#pragma unroll
        for (int r = 0; r < 4; ++r) {
            int p = mi * 16 + quad * 4 + r;
            float S = 0.f, Q = 0.f;
#pragma unroll
            for (int w = 0; w < 8; ++w) { S += psum[w][p][0]; Q += psum[w][p][1]; }
            float mn  = S * (1.f / 512.f);
            float var = Q * (1.f / 512.f) - mn * mn;
            mean[mi][r] = mn;
            rstd[mi][r] = rsqrtf(fmaxf(var, 0.f) + 1e-5f);
        }

    float lgv[4], lbv[4];
#pragma unroll
    for (int ni = 0; ni < 4; ++ni) {
        int c = wid * 64 + ni * 16 + l16;
        lgv[ni] = lng[c]; lbv[ni] = lnb[c];
    }
#pragma unroll
    for (int mi = 0; mi < 2; ++mi)
#pragma unroll
        for (int ni = 0; ni < 4; ++ni) {
            int c = wid * 64 + ni * 16 + l16;
            size_t base = ((size_t)(b * C_ + c)) * N_ + pt * 32 + mi * 16 + quad * 4;
            f32x4 xr = *(const f32x4*)(x + base);
            f32x4 o;
#pragma unroll
            for (int r = 0; r < 4; ++r)
                o[r] = gv * ((acc[mi][ni][r] - mean[mi][r]) * rstd[mi][r] * lgv[ni]
                             + lbv[ni]) + xr[r];
            *(f32x4*)(out + base) = o;
        }
}

// ======================= fallback (R8-proven scalar pipeline, f32)
__global__ void k_qkv8f(const float* __restrict__ x, const float* __restrict__ wq,
                        const float* __restrict__ wk, const float* __restrict__ wv,
                        float* __restrict__ qa, float* __restrict__ ka,
                        float* __restrict__ va, int g0) {
    int idx = blockIdx.x * 256 + threadIdx.x;
    int m = idx & 63, n = (idx >> 6) & 1023, Gl = (idx >> 16) & 1, mat = idx >> 17;
    int G = g0 + Gl, b = G >> 3, hb = G & 7;
    int p = hb * 128 + (n >> 3), o = (n & 7) * 64 + m;
    const float* w = (mat == 0) ? wq : (mat == 1) ? wk : wv;
    float acc = 0.f;
    for (int c = 0; c < C_; ++c)
        acc += w[(size_t)o * C_ + c] * x[((size_t)b * C_ + c) * N_ + p];
    float* dst = (mat == 0) ? qa : (mat == 1) ? ka : va;
    dst[((size_t)Gl * N_ + n) * HD_ + m] = acc;
}
__global__ void k_attn8f(const float* __restrict__ qa, const float* __restrict__ ka,
                         const float* __restrict__ va, float* __restrict__ ac, int g0) {
    int idx = blockIdx.x * 256 + threadIdx.x;
    int i = idx & 1023, Gl = (idx >> 10) & 1, G = g0 + Gl;
    const float* qrow = qa + ((size_t)Gl * N_ + i) * HD_;
    float q[HD_];
    for (int m = 0; m < HD_; ++m) q[m] = qrow[m];
    const float* kb = ka + (size_t)Gl * N_ * HD_;
    const float* vb = va + (size_t)Gl * N_ * HD_;
    float mx = -1e30f;
    for (int j = 0; j < N_; ++j) {
        float s = 0.f;
        for (int m = 0; m < HD_; ++m) s += q[m] * kb[j * HD_ + m];
        mx = fmaxf(mx, s);
    }
    mx *= 0.125f;
    float l = 0.f, ov[HD_];
    for (int m = 0; m < HD_; ++m) ov[m] = 0.f;
    for (int j = 0; j < N_; ++j) {
        float s = 0.f;
        for (int m = 0; m < HD_; ++m) s += q[m] * kb[j * HD_ + m];
        float pj = __expf(s * 0.125f - mx);
        l += pj;
        for (int m = 0; m < HD_; ++m) ov[m] += pj * vb[j * HD_ + m];
    }
    float inv = 1.0f / l;
    int b = G >> 3, hb = G & 7;
    int p = hb * 128 + (i >> 3), cb = (i & 7) * 64;
    for (int m = 0; m < HD_; ++m)
        ac[((size_t)b * C_ + cb + m) * N_ + p] = ov[m] * inv;
}
__global__ void k_oln8f(float* __restrict__ ac, const float* __restrict__ wo,
                        const float* __restrict__ x, const float* __restrict__ lng,
                        const float* __restrict__ lnb, const float* __restrict__ gm) {
    int tid = threadIdx.x, lane = tid & 63, wid = tid >> 6;
    int bp = blockIdx.x * 4 + wid;
    int b = bp >> 10, p = bp & 1023;
    float oc[8];
    for (int h = 0; h < 8; ++h) oc[h] = 0.f;
    for (int c = 0; c < C_; ++c) {
        float cv = ac[((size_t)b * C_ + c) * N_ + p];
        for (int h = 0; h < 8; ++h)
            oc[h] += wo[(size_t)(h * 64 + lane) * C_ + c] * cv;
    }
    float s = 0.f, ss = 0.f;
    for (int h = 0; h < 8; ++h) { s += oc[h]; ss += oc[h] * oc[h]; }
    for (int d = 1; d < 64; d <<= 1) { s += __shfl_xor(s, d, 64); ss += __shfl_xor(ss, d, 64); }
    float mean = s * (1.f / 512.f);
    float var  = ss * (1.f / 512.f) - mean * mean;
    float rstd = rsqrtf(fmaxf(var, 0.f) + 1e-5f);
    float g = gm[0];
    for (int h = 0; h < 8; ++h) {
        int o = h * 64 + lane;
        float xv = x[((size_t)b * C_ + o) * N_ + p];
        ac[((size_t)b * C_ + o) * N_ + p] =
            g * ((oc[h] - mean) * rstd * lng[o] + lnb[o]) + xv;
    }
}

// ---------------------------------------------------------------------------
extern "C" void kernel_launch(void* const* d_in, const int* in_sizes, int n_in,
                              void* d_out, int out_size, void* d_ws, size_t ws_size,
                              hipStream_t stream) {
    const float* x   = (const float*)d_in[0];
    const float* wq  = (const float*)d_in[1];
    const float* wk  = (const float*)d_in[2];
    const float* wv  = (const float*)d_in[3];
    const float* wo  = (const float*)d_in[4];
    const float* lng = (const float*)d_in[5];
    const float* lnb = (const float*)d_in[6];
    const float* gm  = (const float*)d_in[7];
    float* out = (float*)d_out;
    char* wsb = (char*)d_ws;

    if (ws_size >= ((size_t)18 << 20)) {
        __bf16* xt   = (__bf16*)wsb;
        __bf16* wcat = (__bf16*)(wsb + ((size_t)8 << 20));
        __bf16* Qa   = (__bf16*)(wsb + ((size_t)10 << 20));
        __bf16* Ka   = (__bf16*)d_out;
        __bf16* VaT  = (__bf16*)((char*)d_out + ((size_t)8 << 20));
        __bf16* ap   = xt;
        __bf16* wob  = wcat + 3 * 262144;

        k_prep <<<2048, 256, 0, stream>>>(x, wq, wk, wv, wo, xt, wcat);
        k_qkv  <<<768,  256, 0, stream>>>(xt, wcat, Qa, Ka, VaT);
        k_attn <<<256,  512, 0, stream>>>(Qa, Ka, VaT, ap);
        k_oln  <<<256,  512, 0, stream>>>(ap, wob, x, lng, lnb, gm, out);
    } else {
        float* qa = (float*)(wsb + 256);
        float* ka = qa + 2 * N_ * HD_;
        float* va = ka + 2 * N_ * HD_;
        for (int g0 = 0; g0 < 64; g0 += 2) {
            k_qkv8f <<<1536, 256, 0, stream>>>(x, wq, wk, wv, qa, ka, va, g0);
            k_attn8f<<<8,    256, 0, stream>>>(qa, ka, va, out, g0);
        }
        k_oln8f<<<2048, 256, 0, stream>>>(out, wo, x, lng, lnb, gm);
    }
}